// Round 4
// baseline (200.009 us; speedup 1.0000x reference)
//
#include <hip/hip_runtime.h>
#include <math.h>

// Problem constants: L=4, B=8, Ns=1200, Nl=128, C=768, H=W=448, strides 8/28
constexpr int L_  = 4;
constexpr int B_  = 8;
constexpr int NS  = 1200;
constexpr int NL  = 128;
constexpr int C_  = 768;
constexpr int H_  = 448;
constexpr int W_  = 448;
constexpr int NVS = 3136;   // (448/8)^2
constexpr int NVL = 256;    // (448/28)^2
constexpr int ROWS_S = L_ * B_ * NS;   // 38400
constexpr int ROWS_L = L_ * B_ * NL;   // 4096
constexpr int RPB    = 16;             // rows per block in k_dist
constexpr int BLKS_S = ROWS_S / RPB;   // 2400
constexpr int BLKS_L = ROWS_L / RPB;   // 256

// ---------------------------------------------------------------------------
// K1: valid masks from f_k + zero the completion counter. (No cv zeroing
// needed anymore: nz bytes are unconditionally written by k_dist.)
__global__ __launch_bounds__(256)
void k_prep(const float* __restrict__ f_k,
            unsigned char* __restrict__ valid_s,
            unsigned char* __restrict__ valid_l,
            int* __restrict__ counter) {
    int i = blockIdx.x * 256 + threadIdx.x;
    if (i == 0) *counter = 0;
    if (i < B_ * NVS) {
        int b = i / NVS, p = i - b * NVS;
        int r = p / 56, c = p - r * 56;
        valid_s[i] = (f_k[b * H_ * W_ + r * 8 * W_ + c * 8] > 0.f) ? 1 : 0;
    } else {
        int j = i - B_ * NVS;
        if (j < B_ * NVL) {
            int b = j / NVL, p = j - b * NVL;
            int r = p / 16, c = p - r * 16;
            valid_l[j] = (f_k[b * H_ * W_ + r * 28 * W_ + c * 28] > 0.f) ? 1 : 0;
        }
    }
}

// ---------------------------------------------------------------------------
// K2: distances + per-row nonzero bytes. One block = 16 consecutive rows of
// ONE (l,b). Anchor loaded once per wave. nz layout: [l][n][b] (byte),
// written unconditionally (every byte exactly once -> no init, no race).
__global__ __launch_bounds__(256)
void k_dist(const float* __restrict__ sel_s, const float* __restrict__ sel_l,
            const float* __restrict__ ker_s, const float* __restrict__ ker_l,
            float* __restrict__ d_s, float* __restrict__ d_l,
            unsigned char* __restrict__ nz_s, unsigned char* __restrict__ nz_l) {
    const int lane = threadIdx.x & 63;
    const int wid  = threadIdx.x >> 6;
    const int blk  = blockIdx.x;

    const float* sel; const float* ker; float* dout; unsigned char* nzout;
    int base, N;
    if (blk < BLKS_S) { base = blk * RPB;            N = NS; sel = sel_s; ker = ker_s; dout = d_s; nzout = nz_s; }
    else              { base = (blk - BLKS_S) * RPB; N = NL; sel = sel_l; ker = ker_l; dout = d_l; nzout = nz_l; }
    const int lb = base / N;           // block-uniform
    const int l  = lb >> 3, b = lb & 7;

    const float4* __restrict__ arow = (const float4*)(ker + lb * C_);
    float4 a0 = arow[lane], a1 = arow[64 + lane], a2 = arow[128 + lane];

    const int r0 = base + wid * 4;
    float4 s[4][3];
#pragma unroll
    for (int k = 0; k < 4; ++k) {
        const float4* __restrict__ srow = (const float4*)(sel + (r0 + k) * C_);
        s[k][0] = srow[lane];
        s[k][1] = srow[64 + lane];
        s[k][2] = srow[128 + lane];
    }
#pragma unroll
    for (int k = 0; k < 4; ++k) {
        float acc = 0.f; int nz = 0;
        {
            float4 sv = s[k][0];
            float dx = a0.x - sv.x, dy = a0.y - sv.y, dz = a0.z - sv.z, dw = a0.w - sv.w;
            acc += dx*dx + dy*dy + dz*dz + dw*dw;
            nz |= (sv.x != 0.f) || (sv.y != 0.f) || (sv.z != 0.f) || (sv.w != 0.f);
        }
        {
            float4 sv = s[k][1];
            float dx = a1.x - sv.x, dy = a1.y - sv.y, dz = a1.z - sv.z, dw = a1.w - sv.w;
            acc += dx*dx + dy*dy + dz*dz + dw*dw;
            nz |= (sv.x != 0.f) || (sv.y != 0.f) || (sv.z != 0.f) || (sv.w != 0.f);
        }
        {
            float4 sv = s[k][2];
            float dx = a2.x - sv.x, dy = a2.y - sv.y, dz = a2.z - sv.z, dw = a2.w - sv.w;
            acc += dx*dx + dy*dy + dz*dz + dw*dw;
            nz |= (sv.x != 0.f) || (sv.y != 0.f) || (sv.z != 0.f) || (sv.w != 0.f);
        }
#pragma unroll
        for (int off = 32; off >= 1; off >>= 1) acc += __shfl_xor(acc, off, 64);
        int wnz = __any(nz);
        if (lane == 0) {
            const int r = r0 + k;
            const int n = r - lb * N;
            dout[r] = sqrtf(acc);
            nzout[(l * N + n) * 8 + b] = (unsigned char)(wnz ? 1 : 0);
        }
    }
}

// ---------------------------------------------------------------------------
// K3: stats + final. 64 blocks: blk<32 -> scale s (lb=blk), blk>=32 -> scale
// l (lb=blk-32). col_valid = (uint64 of 8 nz bytes) != 0. Last-done block
// applies act_l &= act_s coupling and writes the scalar.
__global__ __launch_bounds__(256)
void k_stats(const float* __restrict__ d_s, const float* __restrict__ d_l,
             const int* __restrict__ idx_s, const int* __restrict__ idx_l,
             const unsigned char* __restrict__ valid_s,
             const unsigned char* __restrict__ valid_l,
             const unsigned char* __restrict__ nz_s,
             const unsigned char* __restrict__ nz_l,
             float* __restrict__ res,      // 128 floats: (loss, act) per blk
             int* __restrict__ counter,
             float* __restrict__ out) {
    const int blk = blockIdx.x;
    const int sc  = blk >> 5;              // 0 = small, 1 = large
    const int lb  = blk & 31;
    const int l = lb >> 3, b = lb & 7;
    const int tid = threadIdx.x;

    const int N  = sc ? NL : NS;
    const int Nv = sc ? NVL : NVS;
    const float* d           = sc ? d_l : d_s;
    const int* idx           = sc ? idx_l : idx_s;
    const unsigned char* val = sc ? valid_l : valid_s;
    const unsigned long long* nz64 =
        (const unsigned long long*)((sc ? nz_l : nz_s) + (size_t)l * N * 8);

    float sp = 0.f, sn = 0.f;
    int   cp = 0,   cn = 0;
    const int rb = lb * N;
    for (int n = tid; n < N; n += 256) {
        float dv   = d[rb + n];
        int member = val[b * Nv + idx[rb + n]];
        int colv   = (nz64[n] != 0ull) ? 1 : 0;
        int pos = member & colv;
        int neg = (member ^ 1) & colv;
        sp += pos ? dv : 0.f;
        sn += neg ? dv : 0.f;
        cp += pos;
        cn += neg;
    }
#pragma unroll
    for (int off = 32; off >= 1; off >>= 1) {
        sp += __shfl_xor(sp, off, 64);
        sn += __shfl_xor(sn, off, 64);
        cp += __shfl_xor(cp, off, 64);
        cn += __shfl_xor(cn, off, 64);
    }
    __shared__ float wsp[4], wsn[4];
    __shared__ int   wcp[4], wcn[4];
    __shared__ int   islast;
    const int wid = tid >> 6, lane = tid & 63;
    if (lane == 0) { wsp[wid] = sp; wsn[wid] = sn; wcp[wid] = cp; wcn[wid] = cn; }
    if (tid == 0) islast = 0;
    __syncthreads();

    if (tid == 0) {
        float SP = 0.f, SN = 0.f; int CP = 0, CN = 0;
        for (int w = 0; w < 4; ++w) { SP += wsp[w]; SN += wsn[w]; CP += wcp[w]; CN += wcn[w]; }
        float ap = SP / (float)(CP > 0 ? CP : 1);
        float an = SN / (float)(CN > 0 ? CN : 1);
        float x  = ap - an;
        float lossv = fmaxf(x, 0.f) + log1pf(expf(-fabsf(x)));
        float actv  = (CP > 0 && CN > 0) ? 1.f : 0.f;
        __hip_atomic_store(&res[2 * blk],     lossv, __ATOMIC_RELAXED, __HIP_MEMORY_SCOPE_AGENT);
        __hip_atomic_store(&res[2 * blk + 1], actv,  __ATOMIC_RELAXED, __HIP_MEMORY_SCOPE_AGENT);
        int old = __hip_atomic_fetch_add(counter, 1, __ATOMIC_ACQ_REL, __HIP_MEMORY_SCOPE_AGENT);
        islast = (old == 63) ? 1 : 0;
    }
    __syncthreads();
    if (islast && wid == 0) {
        float total = 0.f, times = 0.f;
        if (lane < 32) {
            float ls = __hip_atomic_load(&res[2 * lane],            __ATOMIC_RELAXED, __HIP_MEMORY_SCOPE_AGENT);
            float as = __hip_atomic_load(&res[2 * lane + 1],        __ATOMIC_RELAXED, __HIP_MEMORY_SCOPE_AGENT);
            float ll = __hip_atomic_load(&res[2 * (32 + lane)],     __ATOMIC_RELAXED, __HIP_MEMORY_SCOPE_AGENT);
            float al = __hip_atomic_load(&res[2 * (32 + lane) + 1], __ATOMIC_RELAXED, __HIP_MEMORY_SCOPE_AGENT);
            al *= as;                       // act_l &= act_s
            total = as * ls + al * ll;
            times = as + al;
        }
#pragma unroll
        for (int off = 32; off >= 1; off >>= 1) {
            total += __shfl_xor(total, off, 64);
            times += __shfl_xor(times, off, 64);
        }
        if (lane == 0) out[0] = (times > 0.f) ? (total / times) : 0.f;
    }
}

// ---------------------------------------------------------------------------
extern "C" void kernel_launch(void* const* d_in, const int* in_sizes, int n_in,
                              void* d_out, int out_size, void* d_ws, size_t ws_size,
                              hipStream_t stream) {
    const float* sel_s = (const float*)d_in[0];
    const int*   idx_s = (const int*)  d_in[1];
    const float* sel_l = (const float*)d_in[2];
    const int*   idx_l = (const int*)  d_in[3];
    const float* ker_s = (const float*)d_in[4];
    const float* ker_l = (const float*)d_in[5];
    const float* f_k   = (const float*)d_in[6];
    float* out = (float*)d_out;

    char* base = (char*)d_ws;
    size_t o = 0;
    auto alloc = [&](size_t sz) -> char* {
        char* p = base + o;
        o += (sz + 255) & ~(size_t)255;
        return p;
    };
    unsigned char* valid_s = (unsigned char*)alloc(B_ * NVS);
    unsigned char* valid_l = (unsigned char*)alloc(B_ * NVL);
    unsigned char* nz_s    = (unsigned char*)alloc((size_t)L_ * NS * 8);
    unsigned char* nz_l    = (unsigned char*)alloc((size_t)L_ * NL * 8);
    float* d_s   = (float*)alloc(ROWS_S * sizeof(float));
    float* d_l   = (float*)alloc(ROWS_L * sizeof(float));
    float* res   = (float*)alloc(128 * sizeof(float));
    int*   cnt   = (int*)alloc(sizeof(int));

    k_prep<<<(B_ * NVS + B_ * NVL + 255) / 256, 256, 0, stream>>>(f_k, valid_s, valid_l, cnt);
    k_dist<<<BLKS_S + BLKS_L, 256, 0, stream>>>(sel_s, sel_l, ker_s, ker_l, d_s, d_l, nz_s, nz_l);
    k_stats<<<64, 256, 0, stream>>>(d_s, d_l, idx_s, idx_l, valid_s, valid_l,
                                    nz_s, nz_l, res, cnt, out);
}